// Round 4
// baseline (388.041 us; speedup 1.0000x reference)
//
#include <hip/hip_runtime.h>

#define BB 2048
#define K 32
#define ROW 2056          // L1 + P floats per ft_weight row
#define L1D 2048
#define NFEAT 22528
#define NSLICE 32         // 64 cols per slice
#define SCOLS 64

typedef unsigned short us8 __attribute__((ext_vector_type(8)));
typedef float f8 __attribute__((ext_vector_type(8)));

// workspace layout
#define TBLS_BYTES ((size_t)NFEAT * 2048 * 2)        // 92,274,688 (slice-major bf16 table)
#define W1_ELEMS   ((size_t)8 * 16 * L1D)            // 262,144
#define W1_OFF     TBLS_BYTES
#define G0_OFF     (TBLS_BYTES + W1_ELEMS * 2)       // 92,798,976 (16B aligned)
#define G_BYTES    ((size_t)BB * L1D * 4)            // 16,777,216
#define G1_OFF     (G0_OFF + G_BYTES)
#define WS_NEEDED  (G1_OFF + G_BYTES)                // ~126.4 MB

__device__ __forceinline__ float bf2f(unsigned short s) {
    union { unsigned int u; float f; } v; v.u = ((unsigned int)s) << 16; return v.f;
}

__device__ __forceinline__ unsigned short f2bf(float f) {
    union { float f; unsigned int u; } v; v.f = f;
    const unsigned int u = v.u;
    return (unsigned short)((u + 0x7fffu + ((u >> 16) & 1u)) >> 16);  // RNE; inputs finite
}

__device__ __forceinline__ void fma4(float4& a, float v, const float4 t) {
    a.x = fmaf(v, t.x, a.x); a.y = fmaf(v, t.y, a.y);
    a.z = fmaf(v, t.z, a.z); a.w = fmaf(v, t.w, a.w);
}

__device__ __forceinline__ float4 add4(float4 a, float4 b) {
    float4 r; r.x = a.x + b.x; r.y = a.y + b.y; r.z = a.z + b.z; r.w = a.w + b.w;
    return r;
}

__device__ __forceinline__ float4 mix4(float ua, float4 a, float ub, float4 b) {
    float4 r;
    r.x = fmaf(ua, a.x, ub * b.x); r.y = fmaf(ua, a.y, ub * b.y);
    r.z = fmaf(ua, a.z, ub * b.z); r.w = fmaf(ua, a.w, ub * b.w);
    return r;
}

__device__ __forceinline__ float lsq1(float g, float s) {
    return rintf(fminf(fmaxf(g / s, 0.f), 255.f)) * s;
}

__device__ __forceinline__ float4 lsq4(float4 g, float s) {
    float4 r;
    r.x = lsq1(g.x, s); r.y = lsq1(g.y, s); r.z = lsq1(g.z, s); r.w = lsq1(g.w, s);
    return r;
}

__device__ __forceinline__ float4 mul4(float4 a, float4 b) {
    float4 r; r.x = a.x * b.x; r.y = a.y * b.y; r.z = a.z * b.z; r.w = a.w * b.w;
    return r;
}

// ---- streaming fp32 -> bf16 (used for W1) ----
__global__ __launch_bounds__(256) void conv_bf16(const float* __restrict__ src,
                                                 unsigned short* __restrict__ dst,
                                                 int n4) {
    int i = blockIdx.x * 256 + threadIdx.x;
    const int stride = gridDim.x * 256;
    for (; i < n4; i += stride) {
        const float4 v = ((const float4*)src)[i];
        ushort4 o;
        o.x = f2bf(v.x); o.y = f2bf(v.y); o.z = f2bf(v.z); o.w = f2bf(v.w);
        ((ushort4*)dst)[i] = o;
    }
}

// ---- fp32 table -> slice-major bf16: tblS[slice][row][64] ----
// wave task = (row-group of 8, slice); lane = (row-in-group, col-oct)
__global__ __launch_bounds__(256) void conv_tblS(const float* __restrict__ src,
                                                 unsigned short* __restrict__ dst) {
    const int lane = threadIdx.x & 63;
    const int wid  = (blockIdx.x * 256 + threadIdx.x) >> 6;
    const int nw   = (gridDim.x * 256) >> 6;
    const int rr = lane >> 3, oc = lane & 7;
    const int ntask = (NFEAT / 8) * NSLICE;     // 90112
    for (int task = wid; task < ntask; task += nw) {
        const int rg = task >> 5;               // /NSLICE
        const int s  = task & (NSLICE - 1);
        const int row = rg * 8 + rr;
        const float* p = src + (size_t)row * ROW + s * SCOLS + oc * 8;
        const float4 a = ((const float4*)p)[0];
        const float4 b = ((const float4*)p)[1];
        us8 o;
        o[0] = f2bf(a.x); o[1] = f2bf(a.y); o[2] = f2bf(a.z); o[3] = f2bf(a.w);
        o[4] = f2bf(b.x); o[5] = f2bf(b.y); o[6] = f2bf(b.z); o[7] = f2bf(b.w);
        *(us8*)(dst + ((size_t)s * NFEAT + row) * SCOLS + oc * 8) = o;
        // wave writes 8 rows x 128B = contiguous 1KB in slice-major layout
    }
}

// ---- slice gather: block = (slice, 32-sample group), 1024 thr, 4-way k-split ----
// blockIdx ordering pins one slice per XCD per resident window:
//   p = blk>>8, r = blk&255 ; slice = (r&7) + 8*(p>>1) ; group = (r>>3) + 32*(p&1)
__global__ __launch_bounds__(1024, 8) void gather_slices(
    const int*   __restrict__ widx, const float* __restrict__ wval,
    const int*   __restrict__ bidx, const float* __restrict__ bval,
    const unsigned short* __restrict__ tblS,
    float* __restrict__ G0, float* __restrict__ G1)
{
    const int t   = threadIdx.x;
    const int blk = blockIdx.x;
    const int p = blk >> 8, r = blk & 255;
    const int slice = (r & 7) + 8 * (p >> 1);
    const int group = (r >> 3) + 32 * (p & 1);
    const int ks = t >> 8, rem = t & 255;
    const int sl = rem >> 3, oct = rem & 7;

    __shared__ int   sWI[1024]; __shared__ float sWV[1024];
    __shared__ int   sBI[1024]; __shared__ float sBV[1024];
    __shared__ float sAcc[3 * 256 * 8];          // 24 KB, reused for both sides

    const int ibase = group * 1024;              // 32 samples * 32 k
    sWI[t] = widx[ibase + t]; sWV[t] = wval[ibase + t];
    sBI[t] = bidx[ibase + t]; sBV[t] = bval[ibase + t];
    __syncthreads();

    const unsigned short* base = tblS + (size_t)slice * NFEAT * SCOLS + oct * 8;
    f8 aw = (f8)0.f, ab = (f8)0.f;
    const int kb = sl * 32 + ks * 8;
    #pragma unroll
    for (int kk = 0; kk < 8; ++kk) {
        const int   iw = sWI[kb + kk]; const float vw = sWV[kb + kk];
        const int   ib = sBI[kb + kk]; const float vb = sBV[kb + kk];
        const us8 lw = *(const us8*)(base + (size_t)iw * SCOLS);
        const us8 lb = *(const us8*)(base + (size_t)ib * SCOLS);
        #pragma unroll
        for (int j = 0; j < 8; ++j) aw[j] = fmaf(vw, bf2f(lw[j]), aw[j]);
        #pragma unroll
        for (int j = 0; j < 8; ++j) ab[j] = fmaf(vb, bf2f(lb[j]), ab[j]);
    }

    __syncthreads();
    if (ks > 0) *(f8*)(sAcc + ((ks - 1) * 256 + rem) * 8) = aw;
    __syncthreads();
    if (ks == 0) {
        #pragma unroll
        for (int q = 0; q < 3; ++q) aw += *(const f8*)(sAcc + (q * 256 + rem) * 8);
    }
    __syncthreads();
    if (ks > 0) *(f8*)(sAcc + ((ks - 1) * 256 + rem) * 8) = ab;
    __syncthreads();
    if (ks == 0) {
        #pragma unroll
        for (int q = 0; q < 3; ++q) ab += *(const f8*)(sAcc + (q * 256 + rem) * 8);
        const int sample = group * 32 + sl;
        const size_t off = (size_t)sample * 2048 + slice * SCOLS + oct * 8;
        *(f8*)(G0 + off) = aw;
        *(f8*)(G1 + off) = ab;
    }
}

// ---- combine: per-sample bias + mix + LSQ + pair + MLP + psqt ----
__global__ __launch_bounds__(512, 8) void combine(
    const float* __restrict__ us_p, const float* __restrict__ them_p,
    const int* __restrict__ widx, const float* __restrict__ wval,
    const int* __restrict__ bidx, const float* __restrict__ bval,
    const int* __restrict__ psqt_idx, const int* __restrict__ ls_idx,
    const float* __restrict__ ftw,            // fp32 original (psqt only)
    const float* __restrict__ ftb, const float* __restrict__ lsq_s,
    const unsigned short* __restrict__ w1bf,
    const float* __restrict__ b1, const float* __restrict__ W2,
    const float* __restrict__ b2, const float* __restrict__ Wo,
    const float* __restrict__ bo,
    const float* __restrict__ G0, const float* __restrict__ G1,
    float* __restrict__ out)
{
    const int b = blockIdx.x;
    const int t = threadIdx.x;

    __shared__ float4 sQA[512];
    __shared__ float4 sQB[512];
    __shared__ float4 sM[512];
    __shared__ float  sH1t[16];
    __shared__ float  sH1[16];
    __shared__ float  sH2[32];
    __shared__ float  sPsq;

    const float usv = us_p[b];
    const float thv = them_p[b];

    float4 aw = ((const float4*)(G0 + (size_t)b * 2048))[t];
    float4 ab = ((const float4*)(G1 + (size_t)b * 2048))[t];

    // psqt from fp32 table (bias cancels in wps - bps)
    const int pi = psqt_idx[b];
    if (t < 64) {
        const int k = t & 31;
        const int   idx = (t < 32) ? widx[b * K + k] : bidx[b * K + k];
        const float val = (t < 32) ? wval[b * K + k] : bval[b * K + k];
        float c = val * ftw[(size_t)idx * ROW + 2048 + pi];
        c += __shfl_down(c, 16, 32); c += __shfl_down(c, 8, 32);
        c += __shfl_down(c, 4, 32);  c += __shfl_down(c, 2, 32);
        c += __shfl_down(c, 1, 32);
        const float bsum = __shfl(c, 32);
        if (t == 0) sPsq = (c - bsum) * (usv - 0.5f);
    }

    const float s0 = lsq_s[0], s1 = lsq_s[1], s2 = lsq_s[2], s3 = lsq_s[3];
    const float4 bias = ((const float4*)ftb)[t];
    aw = add4(aw, bias);
    ab = add4(ab, bias);
    const float sA = (t < 256) ? s0 : s1;
    const float sB = (t < 256) ? s2 : s3;
    sQA[t] = lsq4(mix4(usv, aw, thv, ab), sA);
    sQB[t] = lsq4(mix4(usv, ab, thv, aw), sB);
    __syncthreads();

    if (t < 256) {
        sM[t]       = mul4(sQA[t], sQA[t + 256]);
        sM[t + 256] = mul4(sQB[t], sQB[t + 256]);
    }
    __syncthreads();

    const int i = ls_idx[b];
    const unsigned short* W1i = w1bf + (size_t)i * 16 * L1D;
    {
        const int o   = t >> 5;
        const int sub = t & 31;
        const ushort4* Wrow = (const ushort4*)(W1i + o * L1D);
        float4 a4 = {0, 0, 0, 0};
        #pragma unroll
        for (int jj = 0; jj < 16; ++jj) {
            const int j4 = sub + (jj << 5);
            const float4  m = sM[j4];
            const ushort4 w = Wrow[j4];
            a4.x = fmaf(m.x, bf2f(w.x), a4.x); a4.y = fmaf(m.y, bf2f(w.y), a4.y);
            a4.z = fmaf(m.z, bf2f(w.z), a4.z); a4.w = fmaf(m.w, bf2f(w.w), a4.w);
        }
        float acc = (a4.x + a4.y) + (a4.z + a4.w);
        acc += __shfl_down(acc, 16, 32); acc += __shfl_down(acc, 8, 32);
        acc += __shfl_down(acc, 4, 32);  acc += __shfl_down(acc, 2, 32);
        acc += __shfl_down(acc, 1, 32);
        if (sub == 0) sH1t[o] = acc;
    }
    __syncthreads();

    if (t < 16) {
        const float v = sH1t[t] + b1[i * 16 + t];
        sH1[t] = fminf(fmaxf(v, 0.f), 1.f);
    }
    __syncthreads();

    if (t < 32) {
        const float* W2i = W2 + (size_t)i * 32 * 16 + t * 16;
        float v = b2[i * 32 + t];
        #pragma unroll
        for (int j = 0; j < 16; ++j) v = fmaf(sH1[j], W2i[j], v);
        sH2[t] = fminf(fmaxf(v, 0.f), 1.f);
    }
    __syncthreads();

    if (t == 0) {
        const float* Woi = Wo + (size_t)i * 32;
        float v = bo[i];
        #pragma unroll
        for (int j = 0; j < 32; ++j) v = fmaf(sH2[j], Woi[j], v);
        out[b] = v + sPsq;
    }
}

// ---- fallback: fully fused fp32 (only if ws too small) ----
__global__ __launch_bounds__(512, 8) void nnue_fwd_f32(
    const float* __restrict__ us_p, const float* __restrict__ them_p,
    const int* __restrict__ widx, const float* __restrict__ wval,
    const int* __restrict__ bidx, const float* __restrict__ bval,
    const int* __restrict__ psqt_idx, const int* __restrict__ ls_idx,
    const float* __restrict__ ftw, const float* __restrict__ ftb,
    const float* __restrict__ lsq_s, const float* __restrict__ W1,
    const float* __restrict__ b1, const float* __restrict__ W2,
    const float* __restrict__ b2, const float* __restrict__ Wo,
    const float* __restrict__ bo, float* __restrict__ out)
{
    const int b = blockIdx.x;
    const int t = threadIdx.x;
    __shared__ float4 sQA[512]; __shared__ float4 sQB[512]; __shared__ float4 sM[512];
    __shared__ float sH1t[16]; __shared__ float sH1[16]; __shared__ float sH2[32];
    __shared__ float sPsq;
    const float usv = us_p[b]; const float thv = them_p[b];
    float4 aw = {0,0,0,0}, ab = {0,0,0,0};
    #pragma unroll 4
    for (int k = 0; k < K; ++k) {
        const int iw = widx[b*K+k]; const float vw = wval[b*K+k];
        const int ib = bidx[b*K+k]; const float vb = bval[b*K+k];
        fma4(aw, vw, ((const float4*)(ftw + (size_t)iw * ROW))[t]);
        fma4(ab, vb, ((const float4*)(ftw + (size_t)ib * ROW))[t]);
    }
    const int pi = psqt_idx[b];
    if (t < 64) {
        const int k = t & 31;
        const int   idx = (t < 32) ? widx[b*K+k] : bidx[b*K+k];
        const float val = (t < 32) ? wval[b*K+k] : bval[b*K+k];
        float c = val * ftw[(size_t)idx * ROW + 2048 + pi];
        c += __shfl_down(c, 16, 32); c += __shfl_down(c, 8, 32);
        c += __shfl_down(c, 4, 32); c += __shfl_down(c, 2, 32); c += __shfl_down(c, 1, 32);
        const float bsum = __shfl(c, 32);
        if (t == 0) sPsq = (c - bsum) * (usv - 0.5f);
    }
    const float s0 = lsq_s[0], s1 = lsq_s[1], s2 = lsq_s[2], s3 = lsq_s[3];
    const float4 bias = ((const float4*)ftb)[t];
    aw = add4(aw, bias); ab = add4(ab, bias);
    const float sA = (t < 256) ? s0 : s1;
    const float sB = (t < 256) ? s2 : s3;
    sQA[t] = lsq4(mix4(usv, aw, thv, ab), sA);
    sQB[t] = lsq4(mix4(usv, ab, thv, aw), sB);
    __syncthreads();
    if (t < 256) { sM[t] = mul4(sQA[t], sQA[t+256]); sM[t+256] = mul4(sQB[t], sQB[t+256]); }
    __syncthreads();
    const int i = ls_idx[b];
    const float* W1i = W1 + (size_t)i * 16 * L1D;
    {
        const int o = t >> 5; const int sub = t & 31;
        const float4* Wrow = (const float4*)(W1i + o * L1D);
        float4 a4 = {0,0,0,0};
        #pragma unroll
        for (int jj = 0; jj < 16; ++jj) {
            const int j4 = sub + (jj << 5);
            const float4 m = sM[j4]; const float4 w = Wrow[j4];
            a4.x = fmaf(m.x, w.x, a4.x); a4.y = fmaf(m.y, w.y, a4.y);
            a4.z = fmaf(m.z, w.z, a4.z); a4.w = fmaf(m.w, w.w, a4.w);
        }
        float acc = (a4.x + a4.y) + (a4.z + a4.w);
        acc += __shfl_down(acc, 16, 32); acc += __shfl_down(acc, 8, 32);
        acc += __shfl_down(acc, 4, 32); acc += __shfl_down(acc, 2, 32); acc += __shfl_down(acc, 1, 32);
        if (sub == 0) sH1t[o] = acc;
    }
    __syncthreads();
    if (t < 16) sH1[t] = fminf(fmaxf(sH1t[t] + b1[i*16+t], 0.f), 1.f);
    __syncthreads();
    if (t < 32) {
        const float* W2i = W2 + (size_t)i * 32 * 16 + t * 16;
        float v = b2[i*32+t];
        #pragma unroll
        for (int j = 0; j < 16; ++j) v = fmaf(sH1[j], W2i[j], v);
        sH2[t] = fminf(fmaxf(v, 0.f), 1.f);
    }
    __syncthreads();
    if (t == 0) {
        const float* Woi = Wo + (size_t)i * 32;
        float v = bo[i];
        #pragma unroll
        for (int j = 0; j < 32; ++j) v = fmaf(sH2[j], Woi[j], v);
        out[b] = v + sPsq;
    }
}

extern "C" void kernel_launch(void* const* d_in, const int* in_sizes, int n_in,
                              void* d_out, int out_size, void* d_ws, size_t ws_size,
                              hipStream_t stream) {
    const float* us_p  = (const float*)d_in[0];
    const float* them  = (const float*)d_in[1];
    const int*   widx  = (const int*)d_in[2];
    const float* wval  = (const float*)d_in[3];
    const int*   bidx  = (const int*)d_in[4];
    const float* bval  = (const float*)d_in[5];
    const int*   pidx  = (const int*)d_in[6];
    const int*   lidx  = (const int*)d_in[7];
    const float* ftw   = (const float*)d_in[8];
    const float* ftb   = (const float*)d_in[9];
    const float* lsqs  = (const float*)d_in[10];
    const float* W1    = (const float*)d_in[11];
    const float* b1    = (const float*)d_in[12];
    const float* W2    = (const float*)d_in[13];
    const float* b2    = (const float*)d_in[14];
    const float* Wo    = (const float*)d_in[15];
    const float* bo    = (const float*)d_in[16];
    float* out = (float*)d_out;

    if (ws_size >= WS_NEEDED) {
        unsigned short* tblS = (unsigned short*)d_ws;
        unsigned short* w1bf = (unsigned short*)((char*)d_ws + W1_OFF);
        float* G0 = (float*)((char*)d_ws + G0_OFF);
        float* G1 = (float*)((char*)d_ws + G1_OFF);
        conv_tblS<<<dim3(2048), dim3(256), 0, stream>>>(ftw, tblS);
        conv_bf16<<<dim3(256), dim3(256), 0, stream>>>(W1, w1bf, (int)(W1_ELEMS / 4));
        gather_slices<<<dim3(2048), dim3(1024), 0, stream>>>(
            widx, wval, bidx, bval, tblS, G0, G1);
        combine<<<dim3(BB), dim3(512), 0, stream>>>(
            us_p, them, widx, wval, bidx, bval, pidx, lidx,
            ftw, ftb, lsqs, w1bf, b1, W2, b2, Wo, bo, G0, G1, out);
    } else {
        nnue_fwd_f32<<<dim3(BB), dim3(512), 0, stream>>>(
            us_p, them, widx, wval, bidx, bval, pidx, lidx,
            ftw, ftb, lsqs, W1, b1, W2, b2, Wo, bo, out);
    }
}

// Round 5
// 378.594 us; speedup vs baseline: 1.0250x; 1.0250x over previous
//
#include <hip/hip_runtime.h>

#define BB 2048
#define K 32
#define ROW 2056          // L1 + P floats per fp32 ft_weight row
#define L1D 2048
#define NFEAT 22528

typedef unsigned short us8 __attribute__((ext_vector_type(8)));
typedef float f8 __attribute__((ext_vector_type(8)));

// workspace: compact bf16 table [NFEAT][2048] + bf16 W1 [8][16][2048]
#define TBLC_BYTES ((size_t)NFEAT * 2048 * 2)        // 92,274,688
#define W1_ELEMS   ((size_t)8 * 16 * L1D)            // 262,144
#define W1_OFF     TBLC_BYTES
#define WS_NEEDED  (TBLC_BYTES + W1_ELEMS * 2)

#define TBL_N8 (NFEAT * 256)                         // us8 chunks in compact table
#define W1_N8  (W1_ELEMS / 8)

__device__ __forceinline__ float bf2f(unsigned short s) {
    union { unsigned int u; float f; } v; v.u = ((unsigned int)s) << 16; return v.f;
}

__device__ __forceinline__ unsigned short f2bf(float f) {
    union { float f; unsigned int u; } v; v.f = f;
    const unsigned int u = v.u;
    return (unsigned short)((u + 0x7fffu + ((u >> 16) & 1u)) >> 16);  // RNE; finite inputs
}

__device__ __forceinline__ void fma4(float4& a, float v, const float4 t) {
    a.x = fmaf(v, t.x, a.x); a.y = fmaf(v, t.y, a.y);
    a.z = fmaf(v, t.z, a.z); a.w = fmaf(v, t.w, a.w);
}

__device__ __forceinline__ float4 add4(float4 a, float4 b) {
    float4 r; r.x = a.x + b.x; r.y = a.y + b.y; r.z = a.z + b.z; r.w = a.w + b.w;
    return r;
}

__device__ __forceinline__ float4 mix4(float ua, float4 a, float ub, float4 b) {
    float4 r;
    r.x = fmaf(ua, a.x, ub * b.x); r.y = fmaf(ua, a.y, ub * b.y);
    r.z = fmaf(ua, a.z, ub * b.z); r.w = fmaf(ua, a.w, ub * b.w);
    return r;
}

__device__ __forceinline__ float lsq1(float g, float s) {
    return rintf(fminf(fmaxf(g / s, 0.f), 255.f)) * s;
}

__device__ __forceinline__ float4 lsq4(float4 g, float s) {
    float4 r;
    r.x = lsq1(g.x, s); r.y = lsq1(g.y, s); r.z = lsq1(g.z, s); r.w = lsq1(g.w, s);
    return r;
}

__device__ __forceinline__ float4 mul4(float4 a, float4 b) {
    float4 r; r.x = a.x * b.x; r.y = a.y * b.y; r.z = a.z * b.z; r.w = a.w * b.w;
    return r;
}

// ---- conv: fp32 -> bf16, compact table (drop psqt cols) + W1, one launch ----
__global__ __launch_bounds__(256) void conv_all(const float* __restrict__ ftw,
                                                const float* __restrict__ W1,
                                                unsigned short* __restrict__ tblc,
                                                unsigned short* __restrict__ w1bf) {
    int i = blockIdx.x * 256 + threadIdx.x;
    const int stride = gridDim.x * 256;
    for (; i < TBL_N8 + W1_N8; i += stride) {
        const float* src;
        unsigned short* dst;
        if (i < TBL_N8) {
            const int row = i >> 8, c = i & 255;
            src = ftw + (size_t)row * ROW + c * 8;
            dst = tblc + ((size_t)row << 11) + c * 8;
        } else {
            const int j = i - TBL_N8;
            src = W1 + (size_t)j * 8;
            dst = w1bf + (size_t)j * 8;
        }
        const float4 a = ((const float4*)src)[0];
        const float4 b = ((const float4*)src)[1];
        us8 o;
        o[0] = f2bf(a.x); o[1] = f2bf(a.y); o[2] = f2bf(a.z); o[3] = f2bf(a.w);
        o[4] = f2bf(b.x); o[5] = f2bf(b.y); o[6] = f2bf(b.z); o[7] = f2bf(b.w);
        *(us8*)dst = o;
    }
}

// ---- fused main: 256 thr/block, 1 sample/block, us8 (16B) gather ----
__global__ __launch_bounds__(256, 8) void nnue_main(
    const float* __restrict__ us_p, const float* __restrict__ them_p,
    const int* __restrict__ widx, const float* __restrict__ wval,
    const int* __restrict__ bidx, const float* __restrict__ bval,
    const int* __restrict__ psqt_idx, const int* __restrict__ ls_idx,
    const float* __restrict__ ftw,            // fp32 original (psqt cols only)
    const float* __restrict__ ftb, const float* __restrict__ lsq_s,
    const unsigned short* __restrict__ tblc,  // bf16 [NFEAT][2048]
    const unsigned short* __restrict__ w1bf,  // bf16 [8][16][2048]
    const float* __restrict__ b1, const float* __restrict__ W2,
    const float* __restrict__ b2, const float* __restrict__ Wo,
    const float* __restrict__ bo, float* __restrict__ out)
{
    const int b = blockIdx.x;
    const int t = threadIdx.x;

    __shared__ f8    sQA[256];     // 8 KB : l0q[0:2048)  -> later M chunks [0:128)
    __shared__ f8    sQB[256];     // 8 KB : l0q[2048:4096) -> later M chunks [128:256)
    __shared__ float sH1t[16];
    __shared__ float sH1[16];
    __shared__ float sH2[32];
    __shared__ float sPsq;

    const float usv = us_p[b];
    const float thv = them_p[b];

    // ---- gather: each thread owns bf16 cols [8t, 8t+8) of both perspectives ----
    f8 aw = (f8)0.f, ab = (f8)0.f;
    #pragma unroll 8
    for (int k = 0; k < K; ++k) {
        const int   iw = widx[b * K + k];
        const float vw = wval[b * K + k];
        const int   ib = bidx[b * K + k];
        const float vb = bval[b * K + k];
        const us8 lw = ((const us8*)(tblc + ((size_t)iw << 11)))[t];
        const us8 lb = ((const us8*)(tblc + ((size_t)ib << 11)))[t];
        #pragma unroll
        for (int j = 0; j < 8; ++j) aw[j] = fmaf(vw, bf2f(lw[j]), aw[j]);
        #pragma unroll
        for (int j = 0; j < 8; ++j) ab[j] = fmaf(vb, bf2f(lb[j]), ab[j]);
    }

    // ---- psqt: fp32 table, selected column only (ft_bias cancels in wps-bps) ----
    const int pi = psqt_idx[b];
    if (t < 64) {
        const int k = t & 31;
        const int   idx = (t < 32) ? widx[b * K + k] : bidx[b * K + k];
        const float val = (t < 32) ? wval[b * K + k] : bval[b * K + k];
        float c = val * ftw[(size_t)idx * ROW + 2048 + pi];
        c += __shfl_down(c, 16, 32); c += __shfl_down(c, 8, 32);
        c += __shfl_down(c, 4, 32);  c += __shfl_down(c, 2, 32);
        c += __shfl_down(c, 1, 32);
        const float bsum = __shfl(c, 32);
        if (t == 0) sPsq = (c - bsum) * (usv - 0.5f);
    }

    // ---- bias + mix + LSQ ----
    const float s0 = lsq_s[0], s1 = lsq_s[1], s2 = lsq_s[2], s3 = lsq_s[3];
    const float4 bl = ((const float4*)ftb)[2 * t];
    const float4 bh = ((const float4*)ftb)[2 * t + 1];
    float4 awl = {aw[0], aw[1], aw[2], aw[3]}, awh = {aw[4], aw[5], aw[6], aw[7]};
    float4 abl = {ab[0], ab[1], ab[2], ab[3]}, abh = {ab[4], ab[5], ab[6], ab[7]};
    awl = add4(awl, bl); awh = add4(awh, bh);
    abl = add4(abl, bl); abh = add4(abh, bh);
    const float sA = (t < 128) ? s0 : s1;   // l0 cols 8t in [0,1024) vs [1024,2048)
    const float sB = (t < 128) ? s2 : s3;   // l0 cols 2048+8t
    const float4 qal = lsq4(mix4(usv, awl, thv, abl), sA);
    const float4 qah = lsq4(mix4(usv, awh, thv, abh), sA);
    const float4 qbl = lsq4(mix4(usv, abl, thv, awl), sB);
    const float4 qbh = lsq4(mix4(usv, abh, thv, awh), sB);
    f8 qa, qb;
    qa[0]=qal.x; qa[1]=qal.y; qa[2]=qal.z; qa[3]=qal.w;
    qa[4]=qah.x; qa[5]=qah.y; qa[6]=qah.z; qa[7]=qah.w;
    qb[0]=qbl.x; qb[1]=qbl.y; qb[2]=qbl.z; qb[3]=qbl.w;
    qb[4]=qbh.x; qb[5]=qbh.y; qb[6]=qbh.z; qb[7]=qbh.w;
    sQA[t] = qa;
    sQB[t] = qb;
    __syncthreads();

    // ---- pairwise multiply, aliased in place ----
    // M chunk c (c<128): s0*s1 -> sQA[c]; chunk c>=128: s2*s3 -> sQB[c]
    if (t < 128) {
        const f8 m = sQA[t] * sQA[t + 128];
        sQA[t] = m;                       // reads: only thread t reads sQA[t]; sQA[t+128] never written
    } else {
        const f8 m = sQB[t - 128] * sQB[t];
        sQB[t] = m;                       // writes only to [128:256); reads of [0:128) untouched
    }
    __syncthreads();

    // ---- h1 = clip(W1[i] @ M + b1[i]); 16 threads/output ----
    const int i = ls_idx[b];
    {
        const int o   = t >> 4;
        const int sub = t & 15;
        const us8* Wrow = (const us8*)(w1bf + (((size_t)i * 16 + o) << 11));
        f8 a8 = (f8)0.f;
        #pragma unroll
        for (int jj = 0; jj < 8; ++jj) {        // chunks c = sub+16*jj < 128
            const int c = sub + (jj << 4);
            const f8 m = sQA[c];
            const us8 w = Wrow[c];
            #pragma unroll
            for (int j = 0; j < 8; ++j) a8[j] = fmaf(m[j], bf2f(w[j]), a8[j]);
        }
        #pragma unroll
        for (int jj = 8; jj < 16; ++jj) {       // chunks c >= 128
            const int c = sub + (jj << 4);
            const f8 m = sQB[c];
            const us8 w = Wrow[c];
            #pragma unroll
            for (int j = 0; j < 8; ++j) a8[j] = fmaf(m[j], bf2f(w[j]), a8[j]);
        }
        float acc = ((a8[0]+a8[1]) + (a8[2]+a8[3])) + ((a8[4]+a8[5]) + (a8[6]+a8[7]));
        acc += __shfl_down(acc, 8, 16); acc += __shfl_down(acc, 4, 16);
        acc += __shfl_down(acc, 2, 16); acc += __shfl_down(acc, 1, 16);
        if (sub == 0) sH1t[o] = acc;
    }
    __syncthreads();

    if (t < 16) {
        const float v = sH1t[t] + b1[i * 16 + t];
        sH1[t] = fminf(fmaxf(v, 0.f), 1.f);
    }
    __syncthreads();

    if (t < 32) {
        const float* W2i = W2 + (size_t)i * 32 * 16 + t * 16;
        float v = b2[i * 32 + t];
        #pragma unroll
        for (int j = 0; j < 16; ++j) v = fmaf(sH1[j], W2i[j], v);
        sH2[t] = fminf(fmaxf(v, 0.f), 1.f);
    }
    __syncthreads();

    if (t == 0) {
        const float* Woi = Wo + (size_t)i * 32;
        float v = bo[i];
        #pragma unroll
        for (int j = 0; j < 32; ++j) v = fmaf(sH2[j], Woi[j], v);
        out[b] = v + sPsq;
    }
}

// ---- fallback: fully fused fp32 (only if ws too small) ----
__global__ __launch_bounds__(512, 8) void nnue_fwd_f32(
    const float* __restrict__ us_p, const float* __restrict__ them_p,
    const int* __restrict__ widx, const float* __restrict__ wval,
    const int* __restrict__ bidx, const float* __restrict__ bval,
    const int* __restrict__ psqt_idx, const int* __restrict__ ls_idx,
    const float* __restrict__ ftw, const float* __restrict__ ftb,
    const float* __restrict__ lsq_s, const float* __restrict__ W1,
    const float* __restrict__ b1, const float* __restrict__ W2,
    const float* __restrict__ b2, const float* __restrict__ Wo,
    const float* __restrict__ bo, float* __restrict__ out)
{
    const int b = blockIdx.x;
    const int t = threadIdx.x;
    __shared__ float4 sQA[512]; __shared__ float4 sQB[512]; __shared__ float4 sM[512];
    __shared__ float sH1t[16]; __shared__ float sH1[16]; __shared__ float sH2[32];
    __shared__ float sPsq;
    const float usv = us_p[b]; const float thv = them_p[b];
    float4 aw = {0,0,0,0}, ab = {0,0,0,0};
    #pragma unroll 4
    for (int k = 0; k < K; ++k) {
        const int iw = widx[b*K+k]; const float vw = wval[b*K+k];
        const int ib = bidx[b*K+k]; const float vb = bval[b*K+k];
        fma4(aw, vw, ((const float4*)(ftw + (size_t)iw * ROW))[t]);
        fma4(ab, vb, ((const float4*)(ftw + (size_t)ib * ROW))[t]);
    }
    const int pi = psqt_idx[b];
    if (t < 64) {
        const int k = t & 31;
        const int   idx = (t < 32) ? widx[b*K+k] : bidx[b*K+k];
        const float val = (t < 32) ? wval[b*K+k] : bval[b*K+k];
        float c = val * ftw[(size_t)idx * ROW + 2048 + pi];
        c += __shfl_down(c, 16, 32); c += __shfl_down(c, 8, 32);
        c += __shfl_down(c, 4, 32); c += __shfl_down(c, 2, 32); c += __shfl_down(c, 1, 32);
        const float bsum = __shfl(c, 32);
        if (t == 0) sPsq = (c - bsum) * (usv - 0.5f);
    }
    const float s0 = lsq_s[0], s1 = lsq_s[1], s2 = lsq_s[2], s3 = lsq_s[3];
    const float4 bias = ((const float4*)ftb)[t];
    aw = add4(aw, bias); ab = add4(ab, bias);
    const float sA = (t < 256) ? s0 : s1;
    const float sB = (t < 256) ? s2 : s3;
    sQA[t] = lsq4(mix4(usv, aw, thv, ab), sA);
    sQB[t] = lsq4(mix4(usv, ab, thv, aw), sB);
    __syncthreads();
    if (t < 256) { sM[t] = mul4(sQA[t], sQA[t+256]); sM[t+256] = mul4(sQB[t], sQB[t+256]); }
    __syncthreads();
    const int i = ls_idx[b];
    const float* W1i = W1 + (size_t)i * 16 * L1D;
    {
        const int o = t >> 5; const int sub = t & 31;
        const float4* Wrow = (const float4*)(W1i + o * L1D);
        float4 a4 = {0,0,0,0};
        #pragma unroll
        for (int jj = 0; jj < 16; ++jj) {
            const int j4 = sub + (jj << 5);
            const float4 m = sM[j4]; const float4 w = Wrow[j4];
            a4.x = fmaf(m.x, w.x, a4.x); a4.y = fmaf(m.y, w.y, a4.y);
            a4.z = fmaf(m.z, w.z, a4.z); a4.w = fmaf(m.w, w.w, a4.w);
        }
        float acc = (a4.x + a4.y) + (a4.z + a4.w);
        acc += __shfl_down(acc, 16, 32); acc += __shfl_down(acc, 8, 32);
        acc += __shfl_down(acc, 4, 32); acc += __shfl_down(acc, 2, 32); acc += __shfl_down(acc, 1, 32);
        if (sub == 0) sH1t[o] = acc;
    }
    __syncthreads();
    if (t < 16) sH1[t] = fminf(fmaxf(sH1t[t] + b1[i*16+t], 0.f), 1.f);
    __syncthreads();
    if (t < 32) {
        const float* W2i = W2 + (size_t)i * 32 * 16 + t * 16;
        float v = b2[i*32+t];
        #pragma unroll
        for (int j = 0; j < 16; ++j) v = fmaf(sH1[j], W2i[j], v);
        sH2[t] = fminf(fmaxf(v, 0.f), 1.f);
    }
    __syncthreads();
    if (t == 0) {
        const float* Woi = Wo + (size_t)i * 32;
        float v = bo[i];
        #pragma unroll
        for (int j = 0; j < 32; ++j) v = fmaf(sH2[j], Woi[j], v);
        out[b] = v + sPsq;
    }
}

extern "C" void kernel_launch(void* const* d_in, const int* in_sizes, int n_in,
                              void* d_out, int out_size, void* d_ws, size_t ws_size,
                              hipStream_t stream) {
    const float* us_p  = (const float*)d_in[0];
    const float* them  = (const float*)d_in[1];
    const int*   widx  = (const int*)d_in[2];
    const float* wval  = (const float*)d_in[3];
    const int*   bidx  = (const int*)d_in[4];
    const float* bval  = (const float*)d_in[5];
    const int*   pidx  = (const int*)d_in[6];
    const int*   lidx  = (const int*)d_in[7];
    const float* ftw   = (const float*)d_in[8];
    const float* ftb   = (const float*)d_in[9];
    const float* lsqs  = (const float*)d_in[10];
    const float* W1    = (const float*)d_in[11];
    const float* b1    = (const float*)d_in[12];
    const float* W2    = (const float*)d_in[13];
    const float* b2    = (const float*)d_in[14];
    const float* Wo    = (const float*)d_in[15];
    const float* bo    = (const float*)d_in[16];
    float* out = (float*)d_out;

    if (ws_size >= WS_NEEDED) {
        unsigned short* tblc = (unsigned short*)d_ws;
        unsigned short* w1bf = (unsigned short*)((char*)d_ws + W1_OFF);
        conv_all<<<dim3(8192), dim3(256), 0, stream>>>(ftw, W1, tblc, w1bf);
        nnue_main<<<dim3(BB), dim3(256), 0, stream>>>(
            us_p, them, widx, wval, bidx, bval, pidx, lidx,
            ftw, ftb, lsqs, tblc, w1bf, b1, W2, b2, Wo, bo, out);
    } else {
        nnue_fwd_f32<<<dim3(BB), dim3(512), 0, stream>>>(
            us_p, them, widx, wval, bidx, bval, pidx, lidx,
            ftw, ftb, lsqs, W1, b1, W2, b2, Wo, bo, out);
    }
}

// Round 6
// 371.628 us; speedup vs baseline: 1.0442x; 1.0187x over previous
//
#include <hip/hip_runtime.h>

#define BB 2048
#define K 32
#define ROW 2056          // L1 + P floats per fp32 ft_weight row
#define L1D 2048
#define NFEAT 22528
#define NSL 32            // macro-slices: cols [32s,32s+32) + [1024+32s,1024+32s+32)

typedef unsigned short us8 __attribute__((ext_vector_type(8)));
typedef float f8 __attribute__((ext_vector_type(8)));

// workspace layout
#define TBL2_BYTES ((size_t)NSL * NFEAT * 64 * 2)    // 92,274,688 (slice-major bf16)
#define W1_ELEMS   ((size_t)8 * 16 * L1D)            // 262,144
#define W1_OFF     TBL2_BYTES
#define G_OFF      (TBL2_BYTES + W1_ELEMS * 2)
#define G_BYTES    ((size_t)BB * L1D * 2)            // 8,388,608 bf16 l0_mixed
#define WS_NEEDED  (G_OFF + G_BYTES)

#define TBL2_N8 (NSL * NFEAT * 8)                    // us8 chunks in slice table
#define W1_N8   ((int)(W1_ELEMS / 8))

__device__ __forceinline__ float bf2f(unsigned short s) {
    union { unsigned int u; float f; } v; v.u = ((unsigned int)s) << 16; return v.f;
}

__device__ __forceinline__ unsigned short f2bf(float f) {
    union { float f; unsigned int u; } v; v.f = f;
    const unsigned int u = v.u;
    return (unsigned short)((u + 0x7fffu + ((u >> 16) & 1u)) >> 16);  // RNE; finite
}

__device__ __forceinline__ void fma4(float4& a, float v, const float4 t) {
    a.x = fmaf(v, t.x, a.x); a.y = fmaf(v, t.y, a.y);
    a.z = fmaf(v, t.z, a.z); a.w = fmaf(v, t.w, a.w);
}

__device__ __forceinline__ float4 add4(float4 a, float4 b) {
    float4 r; r.x = a.x + b.x; r.y = a.y + b.y; r.z = a.z + b.z; r.w = a.w + b.w;
    return r;
}

__device__ __forceinline__ float4 mix4(float ua, float4 a, float ub, float4 b) {
    float4 r;
    r.x = fmaf(ua, a.x, ub * b.x); r.y = fmaf(ua, a.y, ub * b.y);
    r.z = fmaf(ua, a.z, ub * b.z); r.w = fmaf(ua, a.w, ub * b.w);
    return r;
}

__device__ __forceinline__ float lsq1(float g, float s) {
    return rintf(fminf(fmaxf(g / s, 0.f), 255.f)) * s;
}

__device__ __forceinline__ float4 lsq4(float4 g, float s) {
    float4 r;
    r.x = lsq1(g.x, s); r.y = lsq1(g.y, s); r.z = lsq1(g.z, s); r.w = lsq1(g.w, s);
    return r;
}

__device__ __forceinline__ float4 mul4(float4 a, float4 b) {
    float4 r; r.x = a.x * b.x; r.y = a.y * b.y; r.z = a.z * b.z; r.w = a.w * b.w;
    return r;
}

// ---- conv: fp32 -> slice-major bf16 table + bf16 W1, write-sequential ----
__global__ __launch_bounds__(256) void conv_all(const float* __restrict__ ftw,
                                                const float* __restrict__ W1,
                                                unsigned short* __restrict__ tbl2,
                                                unsigned short* __restrict__ w1bf) {
    int i = blockIdx.x * 256 + threadIdx.x;
    const int stride = gridDim.x * 256;
    for (; i < TBL2_N8 + W1_N8; i += stride) {
        const float* src;
        unsigned short* dst;
        if (i < TBL2_N8) {
            const int s   = i / (NFEAT * 8);
            const int rem = i - s * (NFEAT * 8);
            const int r = rem >> 3, o = rem & 7;
            const int col = (o < 4) ? (s * 32 + o * 8) : (1024 + s * 32 + (o - 4) * 8);
            src = ftw + (size_t)r * ROW + col;
            dst = tbl2 + (size_t)i * 8;          // == ((s*NFEAT + r)*64 + o*8)
        } else {
            const int j = i - TBL2_N8;
            src = W1 + (size_t)j * 8;
            dst = w1bf + (size_t)j * 8;
        }
        const float4 a = ((const float4*)src)[0];
        const float4 b = ((const float4*)src)[1];
        us8 o8;
        o8[0] = f2bf(a.x); o8[1] = f2bf(a.y); o8[2] = f2bf(a.z); o8[3] = f2bf(a.w);
        o8[4] = f2bf(b.x); o8[5] = f2bf(b.y); o8[6] = f2bf(b.z); o8[7] = f2bf(b.w);
        *(us8*)dst = o8;
    }
}

// ---- gather+mix: block = (macro-slice, 32-sample group); 512 thr ----
// thread = (sample sl, persp, half, oct4); XCD-phased block ordering.
__global__ __launch_bounds__(512, 8) void gather_mix(
    const float* __restrict__ us_p, const float* __restrict__ them_p,
    const int* __restrict__ widx, const float* __restrict__ wval,
    const int* __restrict__ bidx, const float* __restrict__ bval,
    const float* __restrict__ ftb, const float* __restrict__ lsq_s,
    const unsigned short* __restrict__ tbl2,
    unsigned short* __restrict__ G)
{
    __shared__ char smemA[16384];      // sI[2048] + sV[2048]; later f8 sEx[512]
    __shared__ f8 sQm[256];            // 8 KB
    __shared__ f8 sQs[256];            // 8 KB
    int*   sI  = (int*)smemA;
    float* sV  = (float*)(smemA + 8192);
    f8*    sEx = (f8*)smemA;

    const int blk = blockIdx.x;
    const int p = blk >> 8, r = blk & 255;
    const int slice = (r & 7) + 8 * (p >> 1);    // one slice per XCD per window
    const int group = (r >> 3) + 32 * (p & 1);
    const int t = threadIdx.x;

    const int base = group * 1024;               // 32 samples * 32 k
    sI[t]        = widx[base + t];        sI[512 + t]  = widx[base + 512 + t];
    sI[1024 + t] = bidx[base + t];        sI[1536 + t] = bidx[base + 512 + t];
    sV[t]        = wval[base + t];        sV[512 + t]  = wval[base + 512 + t];
    sV[1024 + t] = bval[base + t];        sV[1536 + t] = bval[base + 512 + t];
    __syncthreads();

    const int sl    = t >> 4;
    const int c     = t & 15;
    const int persp = c >> 3;
    const int ho    = c & 7;       // half*4 + oct
    const int half  = ho >> 2;
    const int oct   = ho & 3;
    const int sample = group * 32 + sl;

    const float usv = us_p[sample];
    const float thv = them_p[sample];
    const float sm  = half ? lsq_s[1] : lsq_s[0];
    const float ss  = half ? lsq_s[3] : lsq_s[2];

    // k-loop: 16 lanes of a sample read w-row 128B + b-row 128B, coalesced
    const unsigned short* tb = tbl2 + (size_t)slice * NFEAT * 64 + half * 32 + oct * 8;
    const int ib = persp * 1024 + sl * 32;
    f8 acc = (f8)0.f;
    #pragma unroll 8
    for (int k = 0; k < 32; ++k) {
        const int   idx = sI[ib + k];
        const float v   = sV[ib + k];
        const us8 L = *(const us8*)(tb + (size_t)idx * 64);
        #pragma unroll
        for (int j = 0; j < 8; ++j) acc[j] = fmaf(v, bf2f(L[j]), acc[j]);
    }

    // + ft_bias (compact col space: half*1024 + 32*slice + 8*oct)
    const int colc = half * 1024 + slice * 32 + oct * 8;
    {
        const float4 b0 = ((const float4*)(ftb + colc))[0];
        const float4 b1v = ((const float4*)(ftb + colc))[1];
        acc[0] += b0.x;  acc[1] += b0.y;  acc[2] += b0.z;  acc[3] += b0.w;
        acc[4] += b1v.x; acc[5] += b1v.y; acc[6] += b1v.z; acc[7] += b1v.w;
    }

    __syncthreads();                 // done with sI/sV, reuse as sEx
    sEx[t] = acc;
    __syncthreads();

    if (persp == 0) {
        const f8 w8 = sEx[t];
        const f8 b8 = sEx[t + 8];    // partner perspective
        f8 qm, qs;
        #pragma unroll
        for (int j = 0; j < 8; ++j) {
            qm[j] = lsq1(fmaf(usv, w8[j], thv * b8[j]), sm);
            qs[j] = lsq1(fmaf(usv, b8[j], thv * w8[j]), ss);
        }
        const int q = sl * 8 + ho;
        sQm[q] = qm;
        sQs[q] = qs;
    }
    __syncthreads();

    if (t < 128) {
        const int sl2 = t >> 2, o2 = t & 3;
        const f8 mlo = sQm[sl2 * 8 + o2] * sQm[sl2 * 8 + 4 + o2];   // s0*s1
        const f8 mhi = sQs[sl2 * 8 + o2] * sQs[sl2 * 8 + 4 + o2];   // s2*s3
        us8 alo, ahi;
        #pragma unroll
        for (int j = 0; j < 8; ++j) { alo[j] = f2bf(mlo[j]); ahi[j] = f2bf(mhi[j]); }
        unsigned short* gp = G + (size_t)(group * 32 + sl2) * 2048;
        *(us8*)(gp + slice * 32 + o2 * 8)        = alo;
        *(us8*)(gp + 1024 + slice * 32 + o2 * 8) = ahi;
    }
}

// ---- combine: W1 matvec + MLP tail + psqt ----
__global__ __launch_bounds__(256, 8) void combine(
    const float* __restrict__ us_p,
    const int* __restrict__ widx, const float* __restrict__ wval,
    const int* __restrict__ bidx, const float* __restrict__ bval,
    const int* __restrict__ psqt_idx, const int* __restrict__ ls_idx,
    const float* __restrict__ ftw,            // fp32 original (psqt cols only)
    const unsigned short* __restrict__ G,     // bf16 l0_mixed [B][2048]
    const unsigned short* __restrict__ w1bf,
    const float* __restrict__ b1, const float* __restrict__ W2,
    const float* __restrict__ b2, const float* __restrict__ Wo,
    const float* __restrict__ bo, float* __restrict__ out)
{
    const int b = blockIdx.x;
    const int t = threadIdx.x;

    __shared__ f8    sM[256];      // 8 KB
    __shared__ float sH1t[16];
    __shared__ float sH1[16];
    __shared__ float sH2[32];
    __shared__ float sPsq;

    const float usv = us_p[b];

    {
        const us8 mu = ((const us8*)(G + (size_t)b * 2048))[t];
        f8 mf;
        #pragma unroll
        for (int j = 0; j < 8; ++j) mf[j] = bf2f(mu[j]);
        sM[t] = mf;
    }

    // psqt: fp32 table, selected column only (ft_bias cancels in wps-bps)
    const int pi = psqt_idx[b];
    if (t < 64) {
        const int k = t & 31;
        const int   idx = (t < 32) ? widx[b * K + k] : bidx[b * K + k];
        const float val = (t < 32) ? wval[b * K + k] : bval[b * K + k];
        float cc = val * ftw[(size_t)idx * ROW + 2048 + pi];
        cc += __shfl_down(cc, 16, 32); cc += __shfl_down(cc, 8, 32);
        cc += __shfl_down(cc, 4, 32);  cc += __shfl_down(cc, 2, 32);
        cc += __shfl_down(cc, 1, 32);
        const float bsum = __shfl(cc, 32);
        if (t == 0) sPsq = (cc - bsum) * (usv - 0.5f);
    }
    __syncthreads();

    const int i = ls_idx[b];
    {
        const int o   = t >> 4;
        const int sub = t & 15;
        const us8* Wrow = (const us8*)(w1bf + (((size_t)i * 16 + o) << 11));
        f8 a8 = (f8)0.f;
        #pragma unroll
        for (int jj = 0; jj < 16; ++jj) {
            const int cidx = sub + (jj << 4);
            const f8 m = sM[cidx];
            const us8 w = Wrow[cidx];
            #pragma unroll
            for (int j = 0; j < 8; ++j) a8[j] = fmaf(m[j], bf2f(w[j]), a8[j]);
        }
        float acc = ((a8[0]+a8[1]) + (a8[2]+a8[3])) + ((a8[4]+a8[5]) + (a8[6]+a8[7]));
        acc += __shfl_down(acc, 8, 16); acc += __shfl_down(acc, 4, 16);
        acc += __shfl_down(acc, 2, 16); acc += __shfl_down(acc, 1, 16);
        if (sub == 0) sH1t[o] = acc;
    }
    __syncthreads();

    if (t < 16) {
        const float v = sH1t[t] + b1[i * 16 + t];
        sH1[t] = fminf(fmaxf(v, 0.f), 1.f);
    }
    __syncthreads();

    if (t < 32) {
        const float* W2i = W2 + (size_t)i * 32 * 16 + t * 16;
        float v = b2[i * 32 + t];
        #pragma unroll
        for (int j = 0; j < 16; ++j) v = fmaf(sH1[j], W2i[j], v);
        sH2[t] = fminf(fmaxf(v, 0.f), 1.f);
    }
    __syncthreads();

    if (t == 0) {
        const float* Woi = Wo + (size_t)i * 32;
        float v = bo[i];
        #pragma unroll
        for (int j = 0; j < 32; ++j) v = fmaf(sH2[j], Woi[j], v);
        out[b] = v + sPsq;
    }
}

// ---- fallback: fully fused fp32 (only if ws too small) ----
__global__ __launch_bounds__(512, 8) void nnue_fwd_f32(
    const float* __restrict__ us_p, const float* __restrict__ them_p,
    const int* __restrict__ widx, const float* __restrict__ wval,
    const int* __restrict__ bidx, const float* __restrict__ bval,
    const int* __restrict__ psqt_idx, const int* __restrict__ ls_idx,
    const float* __restrict__ ftw, const float* __restrict__ ftb,
    const float* __restrict__ lsq_s, const float* __restrict__ W1,
    const float* __restrict__ b1, const float* __restrict__ W2,
    const float* __restrict__ b2, const float* __restrict__ Wo,
    const float* __restrict__ bo, float* __restrict__ out)
{
    const int b = blockIdx.x;
    const int t = threadIdx.x;
    __shared__ float4 sQA[512]; __shared__ float4 sQB[512]; __shared__ float4 sMx[512];
    __shared__ float sH1t[16]; __shared__ float sH1[16]; __shared__ float sH2[32];
    __shared__ float sPsq;
    const float usv = us_p[b]; const float thv = them_p[b];
    float4 aw = {0,0,0,0}, ab = {0,0,0,0};
    #pragma unroll 4
    for (int k = 0; k < K; ++k) {
        const int iw = widx[b*K+k]; const float vw = wval[b*K+k];
        const int ibx = bidx[b*K+k]; const float vb = bval[b*K+k];
        fma4(aw, vw, ((const float4*)(ftw + (size_t)iw * ROW))[t]);
        fma4(ab, vb, ((const float4*)(ftw + (size_t)ibx * ROW))[t]);
    }
    const int pi = psqt_idx[b];
    if (t < 64) {
        const int k = t & 31;
        const int   idx = (t < 32) ? widx[b*K+k] : bidx[b*K+k];
        const float val = (t < 32) ? wval[b*K+k] : bval[b*K+k];
        float cc = val * ftw[(size_t)idx * ROW + 2048 + pi];
        cc += __shfl_down(cc, 16, 32); cc += __shfl_down(cc, 8, 32);
        cc += __shfl_down(cc, 4, 32); cc += __shfl_down(cc, 2, 32); cc += __shfl_down(cc, 1, 32);
        const float bsum = __shfl(cc, 32);
        if (t == 0) sPsq = (cc - bsum) * (usv - 0.5f);
    }
    const float s0 = lsq_s[0], s1 = lsq_s[1], s2 = lsq_s[2], s3 = lsq_s[3];
    const float4 bias = ((const float4*)ftb)[t];
    aw = add4(aw, bias); ab = add4(ab, bias);
    const float sA = (t < 256) ? s0 : s1;
    const float sB = (t < 256) ? s2 : s3;
    sQA[t] = lsq4(mix4(usv, aw, thv, ab), sA);
    sQB[t] = lsq4(mix4(usv, ab, thv, aw), sB);
    __syncthreads();
    if (t < 256) { sMx[t] = mul4(sQA[t], sQA[t+256]); sMx[t+256] = mul4(sQB[t], sQB[t+256]); }
    __syncthreads();
    const int i = ls_idx[b];
    const float* W1i = W1 + (size_t)i * 16 * L1D;
    {
        const int o = t >> 5; const int sub = t & 31;
        const float4* Wrow = (const float4*)(W1i + o * L1D);
        float4 a4 = {0,0,0,0};
        #pragma unroll
        for (int jj = 0; jj < 16; ++jj) {
            const int j4 = sub + (jj << 5);
            const float4 m = sMx[j4]; const float4 w = Wrow[j4];
            a4.x = fmaf(m.x, w.x, a4.x); a4.y = fmaf(m.y, w.y, a4.y);
            a4.z = fmaf(m.z, w.z, a4.z); a4.w = fmaf(m.w, w.w, a4.w);
        }
        float acc = (a4.x + a4.y) + (a4.z + a4.w);
        acc += __shfl_down(acc, 16, 32); acc += __shfl_down(acc, 8, 32);
        acc += __shfl_down(acc, 4, 32); acc += __shfl_down(acc, 2, 32); acc += __shfl_down(acc, 1, 32);
        if (sub == 0) sH1t[o] = acc;
    }
    __syncthreads();
    if (t < 16) sH1[t] = fminf(fmaxf(sH1t[t] + b1[i*16+t], 0.f), 1.f);
    __syncthreads();
    if (t < 32) {
        const float* W2i = W2 + (size_t)i * 32 * 16 + t * 16;
        float v = b2[i*32+t];
        #pragma unroll
        for (int j = 0; j < 16; ++j) v = fmaf(sH1[j], W2i[j], v);
        sH2[t] = fminf(fmaxf(v, 0.f), 1.f);
    }
    __syncthreads();
    if (t == 0) {
        const float* Woi = Wo + (size_t)i * 32;
        float v = bo[i];
        #pragma unroll
        for (int j = 0; j < 32; ++j) v = fmaf(sH2[j], Woi[j], v);
        out[b] = v + sPsq;
    }
}

extern "C" void kernel_launch(void* const* d_in, const int* in_sizes, int n_in,
                              void* d_out, int out_size, void* d_ws, size_t ws_size,
                              hipStream_t stream) {
    const float* us_p  = (const float*)d_in[0];
    const float* them  = (const float*)d_in[1];
    const int*   widx  = (const int*)d_in[2];
    const float* wval  = (const float*)d_in[3];
    const int*   bidx  = (const int*)d_in[4];
    const float* bval  = (const float*)d_in[5];
    const int*   pidx  = (const int*)d_in[6];
    const int*   lidx  = (const int*)d_in[7];
    const float* ftw   = (const float*)d_in[8];
    const float* ftb   = (const float*)d_in[9];
    const float* lsqs  = (const float*)d_in[10];
    const float* W1    = (const float*)d_in[11];
    const float* b1    = (const float*)d_in[12];
    const float* W2    = (const float*)d_in[13];
    const float* b2    = (const float*)d_in[14];
    const float* Wo    = (const float*)d_in[15];
    const float* bo    = (const float*)d_in[16];
    float* out = (float*)d_out;

    if (ws_size >= WS_NEEDED) {
        unsigned short* tbl2 = (unsigned short*)d_ws;
        unsigned short* w1bf = (unsigned short*)((char*)d_ws + W1_OFF);
        unsigned short* G    = (unsigned short*)((char*)d_ws + G_OFF);
        conv_all<<<dim3(8192), dim3(256), 0, stream>>>(ftw, W1, tbl2, w1bf);
        gather_mix<<<dim3(2048), dim3(512), 0, stream>>>(
            us_p, them, widx, wval, bidx, bval, ftb, lsqs, tbl2, G);
        combine<<<dim3(BB), dim3(256), 0, stream>>>(
            us_p, widx, wval, bidx, bval, pidx, lidx,
            ftw, G, w1bf, b1, W2, b2, Wo, bo, out);
    } else {
        nnue_fwd_f32<<<dim3(BB), dim3(512), 0, stream>>>(
            us_p, them, widx, wval, bidx, bval, pidx, lidx,
            ftw, ftb, lsqs, W1, b1, W2, b2, Wo, bo, out);
    }
}

// Round 7
// 342.011 us; speedup vs baseline: 1.1346x; 1.0866x over previous
//
#include <hip/hip_runtime.h>

#define BB 2048
#define K 32
#define ROW 2056          // L1 + P floats per fp32 ft_weight row
#define L1D 2048
#define NFEAT 22528

typedef unsigned short us8 __attribute__((ext_vector_type(8)));
typedef signed char    c8  __attribute__((ext_vector_type(8)));
typedef float          f8  __attribute__((ext_vector_type(8)));

// int8 table scale: clamp +-0.0625, step exactly representable
#define S_T   (0.0625f / 128.0f)     // 4.8828125e-4
#define INV_S (128.0f / 0.0625f)     // 2048.0

// workspace: int8 compact table [NFEAT][2048] + bf16 W1 [8][16][2048]
#define TBLC_BYTES ((size_t)NFEAT * 2048)            // 46,137,344
#define W1_ELEMS   ((size_t)8 * 16 * L1D)            // 262,144
#define W1_OFF     TBLC_BYTES                        // 2048-aligned
#define WS_NEEDED  (TBLC_BYTES + W1_ELEMS * 2)

#define TBL_N8 (NFEAT * 256)                         // 8-elem chunks in table
#define W1_N8  ((int)(W1_ELEMS / 8))

__device__ __forceinline__ float bf2f(unsigned short s) {
    union { unsigned int u; float f; } v; v.u = ((unsigned int)s) << 16; return v.f;
}

__device__ __forceinline__ unsigned short f2bf(float f) {
    union { float f; unsigned int u; } v; v.f = f;
    const unsigned int u = v.u;
    return (unsigned short)((u + 0x7fffu + ((u >> 16) & 1u)) >> 16);  // RNE; finite
}

__device__ __forceinline__ signed char f2i8(float f) {
    return (signed char)(int)rintf(fminf(fmaxf(f * INV_S, -127.f), 127.f));
}

__device__ __forceinline__ void fma4(float4& a, float v, const float4 t) {
    a.x = fmaf(v, t.x, a.x); a.y = fmaf(v, t.y, a.y);
    a.z = fmaf(v, t.z, a.z); a.w = fmaf(v, t.w, a.w);
}

__device__ __forceinline__ float4 add4(float4 a, float4 b) {
    float4 r; r.x = a.x + b.x; r.y = a.y + b.y; r.z = a.z + b.z; r.w = a.w + b.w;
    return r;
}

__device__ __forceinline__ float4 mix4(float ua, float4 a, float ub, float4 b) {
    float4 r;
    r.x = fmaf(ua, a.x, ub * b.x); r.y = fmaf(ua, a.y, ub * b.y);
    r.z = fmaf(ua, a.z, ub * b.z); r.w = fmaf(ua, a.w, ub * b.w);
    return r;
}

__device__ __forceinline__ float lsq1(float g, float s) {
    return rintf(fminf(fmaxf(g / s, 0.f), 255.f)) * s;
}

__device__ __forceinline__ float4 lsq4(float4 g, float s) {
    float4 r;
    r.x = lsq1(g.x, s); r.y = lsq1(g.y, s); r.z = lsq1(g.z, s); r.w = lsq1(g.w, s);
    return r;
}

__device__ __forceinline__ float4 mul4(float4 a, float4 b) {
    float4 r; r.x = a.x * b.x; r.y = a.y * b.y; r.z = a.z * b.z; r.w = a.w * b.w;
    return r;
}

// ---- conv: fp32 -> int8 compact table (drop psqt cols) + bf16 W1 ----
__global__ __launch_bounds__(256) void conv_all(const float* __restrict__ ftw,
                                                const float* __restrict__ W1,
                                                signed char* __restrict__ tblc,
                                                unsigned short* __restrict__ w1bf) {
    int i = blockIdx.x * 256 + threadIdx.x;
    const int stride = gridDim.x * 256;
    for (; i < TBL_N8 + W1_N8; i += stride) {
        if (i < TBL_N8) {
            const int row = i >> 8, c = i & 255;
            const float* src = ftw + (size_t)row * ROW + c * 8;
            const float4 a = ((const float4*)src)[0];
            const float4 b = ((const float4*)src)[1];
            c8 o;
            o[0] = f2i8(a.x); o[1] = f2i8(a.y); o[2] = f2i8(a.z); o[3] = f2i8(a.w);
            o[4] = f2i8(b.x); o[5] = f2i8(b.y); o[6] = f2i8(b.z); o[7] = f2i8(b.w);
            *(c8*)(tblc + ((size_t)row << 11) + c * 8) = o;
        } else {
            const int j = i - TBL_N8;
            const float* src = W1 + (size_t)j * 8;
            const float4 a = ((const float4*)src)[0];
            const float4 b = ((const float4*)src)[1];
            us8 o;
            o[0] = f2bf(a.x); o[1] = f2bf(a.y); o[2] = f2bf(a.z); o[3] = f2bf(a.w);
            o[4] = f2bf(b.x); o[5] = f2bf(b.y); o[6] = f2bf(b.z); o[7] = f2bf(b.w);
            *(us8*)(w1bf + (size_t)j * 8) = o;
        }
    }
}

// ---- fused main: 256 thr/block, 1 sample/block, int8 (8B/lane) gather ----
__global__ __launch_bounds__(256, 8) void nnue_main(
    const float* __restrict__ us_p, const float* __restrict__ them_p,
    const int* __restrict__ widx, const float* __restrict__ wval,
    const int* __restrict__ bidx, const float* __restrict__ bval,
    const int* __restrict__ psqt_idx, const int* __restrict__ ls_idx,
    const float* __restrict__ ftw,            // fp32 original (psqt cols only)
    const float* __restrict__ ftb, const float* __restrict__ lsq_s,
    const signed char* __restrict__ tblc,     // int8 [NFEAT][2048]
    const unsigned short* __restrict__ w1bf,  // bf16 [8][16][2048]
    const float* __restrict__ b1, const float* __restrict__ W2,
    const float* __restrict__ b2, const float* __restrict__ Wo,
    const float* __restrict__ bo, float* __restrict__ out)
{
    const int b = blockIdx.x;
    const int t = threadIdx.x;

    __shared__ f8    sQA[256];     // 8 KB : l0q[0:2048)   -> M chunks [0:128)
    __shared__ f8    sQB[256];     // 8 KB : l0q[2048:4096) -> M chunks [128:256)
    __shared__ float sH1t[16];
    __shared__ float sH1[16];
    __shared__ float sH2[32];
    __shared__ float sPsq;

    const float usv = us_p[b];
    const float thv = them_p[b];

    // ---- gather: thread t owns int8 cols [8t, 8t+8) of both perspectives ----
    // accumulate raw quant values; scale folded into bias step below
    f8 aw = (f8)0.f, ab = (f8)0.f;
    #pragma unroll 8
    for (int k = 0; k < K; ++k) {
        const int   iw = widx[b * K + k];
        const float vw = wval[b * K + k];
        const int   ib = bidx[b * K + k];
        const float vb = bval[b * K + k];
        const c8 lw = ((const c8*)(tblc + ((size_t)iw << 11)))[t];
        const c8 lb = ((const c8*)(tblc + ((size_t)ib << 11)))[t];
        #pragma unroll
        for (int j = 0; j < 8; ++j) aw[j] = fmaf(vw, (float)lw[j], aw[j]);
        #pragma unroll
        for (int j = 0; j < 8; ++j) ab[j] = fmaf(vb, (float)lb[j], ab[j]);
    }

    // ---- psqt: fp32 table, selected column only (ft_bias cancels in wps-bps) ----
    const int pi = psqt_idx[b];
    if (t < 64) {
        const int k = t & 31;
        const int   idx = (t < 32) ? widx[b * K + k] : bidx[b * K + k];
        const float val = (t < 32) ? wval[b * K + k] : bval[b * K + k];
        float c = val * ftw[(size_t)idx * ROW + 2048 + pi];
        c += __shfl_down(c, 16, 32); c += __shfl_down(c, 8, 32);
        c += __shfl_down(c, 4, 32);  c += __shfl_down(c, 2, 32);
        c += __shfl_down(c, 1, 32);
        const float bsum = __shfl(c, 32);
        if (t == 0) sPsq = (c - bsum) * (usv - 0.5f);
    }

    // ---- dequant + bias + mix + LSQ ----
    const float s0 = lsq_s[0], s1 = lsq_s[1], s2 = lsq_s[2], s3 = lsq_s[3];
    const float4 bl = ((const float4*)ftb)[2 * t];
    const float4 bh = ((const float4*)ftb)[2 * t + 1];
    float4 awl, awh, abl, abh;
    awl.x = fmaf(aw[0], S_T, bl.x); awl.y = fmaf(aw[1], S_T, bl.y);
    awl.z = fmaf(aw[2], S_T, bl.z); awl.w = fmaf(aw[3], S_T, bl.w);
    awh.x = fmaf(aw[4], S_T, bh.x); awh.y = fmaf(aw[5], S_T, bh.y);
    awh.z = fmaf(aw[6], S_T, bh.z); awh.w = fmaf(aw[7], S_T, bh.w);
    abl.x = fmaf(ab[0], S_T, bl.x); abl.y = fmaf(ab[1], S_T, bl.y);
    abl.z = fmaf(ab[2], S_T, bl.z); abl.w = fmaf(ab[3], S_T, bl.w);
    abh.x = fmaf(ab[4], S_T, bh.x); abh.y = fmaf(ab[5], S_T, bh.y);
    abh.z = fmaf(ab[6], S_T, bh.z); abh.w = fmaf(ab[7], S_T, bh.w);

    const float sA = (t < 128) ? s0 : s1;   // cols 8t in [0,1024) vs [1024,2048)
    const float sB = (t < 128) ? s2 : s3;
    const float4 qal = lsq4(mix4(usv, awl, thv, abl), sA);
    const float4 qah = lsq4(mix4(usv, awh, thv, abh), sA);
    const float4 qbl = lsq4(mix4(usv, abl, thv, awl), sB);
    const float4 qbh = lsq4(mix4(usv, abh, thv, awh), sB);
    f8 qa, qb;
    qa[0]=qal.x; qa[1]=qal.y; qa[2]=qal.z; qa[3]=qal.w;
    qa[4]=qah.x; qa[5]=qah.y; qa[6]=qah.z; qa[7]=qah.w;
    qb[0]=qbl.x; qb[1]=qbl.y; qb[2]=qbl.z; qb[3]=qbl.w;
    qb[4]=qbh.x; qb[5]=qbh.y; qb[6]=qbh.z; qb[7]=qbh.w;
    sQA[t] = qa;
    sQB[t] = qb;
    __syncthreads();

    // ---- pairwise multiply, aliased in place ----
    if (t < 128) {
        const f8 m = sQA[t] * sQA[t + 128];
        sQA[t] = m;
    } else {
        const f8 m = sQB[t - 128] * sQB[t];
        sQB[t] = m;
    }
    __syncthreads();

    // ---- h1 = clip(W1[i] @ M + b1[i]); 16 threads/output ----
    const int i = ls_idx[b];
    {
        const int o   = t >> 4;
        const int sub = t & 15;
        const us8* Wrow = (const us8*)(w1bf + (((size_t)i * 16 + o) << 11));
        f8 a8 = (f8)0.f;
        #pragma unroll
        for (int jj = 0; jj < 8; ++jj) {
            const int c = sub + (jj << 4);
            const f8 m = sQA[c];
            const us8 w = Wrow[c];
            #pragma unroll
            for (int j = 0; j < 8; ++j) a8[j] = fmaf(m[j], bf2f(w[j]), a8[j]);
        }
        #pragma unroll
        for (int jj = 8; jj < 16; ++jj) {
            const int c = sub + (jj << 4);
            const f8 m = sQB[c];
            const us8 w = Wrow[c];
            #pragma unroll
            for (int j = 0; j < 8; ++j) a8[j] = fmaf(m[j], bf2f(w[j]), a8[j]);
        }
        float acc = ((a8[0]+a8[1]) + (a8[2]+a8[3])) + ((a8[4]+a8[5]) + (a8[6]+a8[7]));
        acc += __shfl_down(acc, 8, 16); acc += __shfl_down(acc, 4, 16);
        acc += __shfl_down(acc, 2, 16); acc += __shfl_down(acc, 1, 16);
        if (sub == 0) sH1t[o] = acc;
    }
    __syncthreads();

    if (t < 16) {
        const float v = sH1t[t] + b1[i * 16 + t];
        sH1[t] = fminf(fmaxf(v, 0.f), 1.f);
    }
    __syncthreads();

    if (t < 32) {
        const float* W2i = W2 + (size_t)i * 32 * 16 + t * 16;
        float v = b2[i * 32 + t];
        #pragma unroll
        for (int j = 0; j < 16; ++j) v = fmaf(sH1[j], W2i[j], v);
        sH2[t] = fminf(fmaxf(v, 0.f), 1.f);
    }
    __syncthreads();

    if (t == 0) {
        const float* Woi = Wo + (size_t)i * 32;
        float v = bo[i];
        #pragma unroll
        for (int j = 0; j < 32; ++j) v = fmaf(sH2[j], Woi[j], v);
        out[b] = v + sPsq;
    }
}

// ---- fallback: fully fused fp32 (only if ws too small) ----
__global__ __launch_bounds__(512, 8) void nnue_fwd_f32(
    const float* __restrict__ us_p, const float* __restrict__ them_p,
    const int* __restrict__ widx, const float* __restrict__ wval,
    const int* __restrict__ bidx, const float* __restrict__ bval,
    const int* __restrict__ psqt_idx, const int* __restrict__ ls_idx,
    const float* __restrict__ ftw, const float* __restrict__ ftb,
    const float* __restrict__ lsq_s, const float* __restrict__ W1,
    const float* __restrict__ b1, const float* __restrict__ W2,
    const float* __restrict__ b2, const float* __restrict__ Wo,
    const float* __restrict__ bo, float* __restrict__ out)
{
    const int b = blockIdx.x;
    const int t = threadIdx.x;
    __shared__ float4 sQA[512]; __shared__ float4 sQB[512]; __shared__ float4 sMx[512];
    __shared__ float sH1t[16]; __shared__ float sH1[16]; __shared__ float sH2[32];
    __shared__ float sPsq;
    const float usv = us_p[b]; const float thv = them_p[b];
    float4 aw = {0,0,0,0}, ab = {0,0,0,0};
    #pragma unroll 4
    for (int k = 0; k < K; ++k) {
        const int iw = widx[b*K+k]; const float vw = wval[b*K+k];
        const int ibx = bidx[b*K+k]; const float vb = bval[b*K+k];
        fma4(aw, vw, ((const float4*)(ftw + (size_t)iw * ROW))[t]);
        fma4(ab, vb, ((const float4*)(ftw + (size_t)ibx * ROW))[t]);
    }
    const int pi = psqt_idx[b];
    if (t < 64) {
        const int k = t & 31;
        const int   idx = (t < 32) ? widx[b*K+k] : bidx[b*K+k];
        const float val = (t < 32) ? wval[b*K+k] : bval[b*K+k];
        float cc = val * ftw[(size_t)idx * ROW + 2048 + pi];
        cc += __shfl_down(cc, 16, 32); cc += __shfl_down(cc, 8, 32);
        cc += __shfl_down(cc, 4, 32); cc += __shfl_down(cc, 2, 32); cc += __shfl_down(cc, 1, 32);
        const float bsum = __shfl(cc, 32);
        if (t == 0) sPsq = (cc - bsum) * (usv - 0.5f);
    }
    const float s0 = lsq_s[0], s1 = lsq_s[1], s2 = lsq_s[2], s3 = lsq_s[3];
    const float4 bias = ((const float4*)ftb)[t];
    aw = add4(aw, bias); ab = add4(ab, bias);
    const float sA = (t < 256) ? s0 : s1;
    const float sB = (t < 256) ? s2 : s3;
    sQA[t] = lsq4(mix4(usv, aw, thv, ab), sA);
    sQB[t] = lsq4(mix4(usv, ab, thv, aw), sB);
    __syncthreads();
    if (t < 256) { sMx[t] = mul4(sQA[t], sQA[t+256]); sMx[t+256] = mul4(sQB[t], sQB[t+256]); }
    __syncthreads();
    const int i = ls_idx[b];
    const float* W1i = W1 + (size_t)i * 16 * L1D;
    {
        const int o = t >> 5; const int sub = t & 31;
        const float4* Wrow = (const float4*)(W1i + o * L1D);
        float4 a4 = {0,0,0,0};
        #pragma unroll
        for (int jj = 0; jj < 16; ++jj) {
            const int j4 = sub + (jj << 5);
            const float4 m = sMx[j4]; const float4 w = Wrow[j4];
            a4.x = fmaf(m.x, w.x, a4.x); a4.y = fmaf(m.y, w.y, a4.y);
            a4.z = fmaf(m.z, w.z, a4.z); a4.w = fmaf(m.w, w.w, a4.w);
        }
        float acc = (a4.x + a4.y) + (a4.z + a4.w);
        acc += __shfl_down(acc, 16, 32); acc += __shfl_down(acc, 8, 32);
        acc += __shfl_down(acc, 4, 32); acc += __shfl_down(acc, 2, 32); acc += __shfl_down(acc, 1, 32);
        if (sub == 0) sH1t[o] = acc;
    }
    __syncthreads();
    if (t < 16) sH1[t] = fminf(fmaxf(sH1t[t] + b1[i*16+t], 0.f), 1.f);
    __syncthreads();
    if (t < 32) {
        const float* W2i = W2 + (size_t)i * 32 * 16 + t * 16;
        float v = b2[i*32+t];
        #pragma unroll
        for (int j = 0; j < 16; ++j) v = fmaf(sH1[j], W2i[j], v);
        sH2[t] = fminf(fmaxf(v, 0.f), 1.f);
    }
    __syncthreads();
    if (t == 0) {
        const float* Woi = Wo + (size_t)i * 32;
        float v = bo[i];
        #pragma unroll
        for (int j = 0; j < 32; ++j) v = fmaf(sH2[j], Woi[j], v);
        out[b] = v + sPsq;
    }
}

extern "C" void kernel_launch(void* const* d_in, const int* in_sizes, int n_in,
                              void* d_out, int out_size, void* d_ws, size_t ws_size,
                              hipStream_t stream) {
    const float* us_p  = (const float*)d_in[0];
    const float* them  = (const float*)d_in[1];
    const int*   widx  = (const int*)d_in[2];
    const float* wval  = (const float*)d_in[3];
    const int*   bidx  = (const int*)d_in[4];
    const float* bval  = (const float*)d_in[5];
    const int*   pidx  = (const int*)d_in[6];
    const int*   lidx  = (const int*)d_in[7];
    const float* ftw   = (const float*)d_in[8];
    const float* ftb   = (const float*)d_in[9];
    const float* lsqs  = (const float*)d_in[10];
    const float* W1    = (const float*)d_in[11];
    const float* b1    = (const float*)d_in[12];
    const float* W2    = (const float*)d_in[13];
    const float* b2    = (const float*)d_in[14];
    const float* Wo    = (const float*)d_in[15];
    const float* bo    = (const float*)d_in[16];
    float* out = (float*)d_out;

    if (ws_size >= WS_NEEDED) {
        signed char*    tblc = (signed char*)d_ws;
        unsigned short* w1bf = (unsigned short*)((char*)d_ws + W1_OFF);
        conv_all<<<dim3(8192), dim3(256), 0, stream>>>(ftw, W1, tblc, w1bf);
        nnue_main<<<dim3(BB), dim3(256), 0, stream>>>(
            us_p, them, widx, wval, bidx, bval, pidx, lidx,
            ftw, ftb, lsqs, tblc, w1bf, b1, W2, b2, Wo, bo, out);
    } else {
        nnue_fwd_f32<<<dim3(BB), dim3(512), 0, stream>>>(
            us_p, them, widx, wval, bidx, bval, pidx, lidx,
            ftw, ftb, lsqs, W1, b1, W2, b2, Wo, bo, out);
    }
}